// Round 3
// baseline (202.828 us; speedup 1.0000x reference)
//
#include <hip/hip_runtime.h>
#include <math.h>

#define S_LEN  4096
#define NCH    64
#define TILE_S 128
#define RPT    16          // s-rows per thread
#define TY     8           // 512 threads = 8 waves
#define HALO_L 31
#define STAGE  (TILE_S + 61)   // 189 staged rows

// 106 fused filter taps, computed on HOST (fp64, bit-matching numpy's index
// math) and passed BY VALUE -> kernarg segment -> scalar s_load in kernel.
struct WtArgs { float w6[62]; float w3[32]; float w1[12]; };

// ---------------------------------------------------------------------------
// out[b][si][s][c] = sum_t w_si[t] * x[b][s+off_si+t][c], zero-padded in s.
// Unified window base = s-31: w6 at u=t (t=0..61), w3 at u=t (t=15..46),
// w1 at u=t (t=25..36) -- all three scales consume the SAME window element
// at tap t, so one streaming pass over t covers everything.
//
// Key structure vs round 2 (which was LDS-issue bound: compiler sank the
// win[77] preload back into ~600+ per-FMA ds_reads, VGPR=56 proved it):
// explicit 20-register circular window, exactly 77 ds_read_b32/thread,
// load of win[t+19] issued 4 taps before first use (prefetch slack).
// ---------------------------------------------------------------------------
__global__ __launch_bounds__(512, 4)
void cwt_main(const float* __restrict__ x, float* __restrict__ out,
              const WtArgs W) {
  __shared__ __align__(16) float lds[STAGE * NCH];  // 48384 B

  const int c   = threadIdx.x;        // 0..63 (lane)
  const int ty  = threadIdx.y;        // 0..7 (wave)
  const int tid = ty * 64 + c;
  const int b   = blockIdx.y;
  const int s0  = blockIdx.x * TILE_S;
  const float* xb = x + (size_t)b * S_LEN * NCH;
  const int row0 = s0 - HALO_L;

  // ---- stage rows [s0-31 .. s0+157] to LDS as float4 (coalesced, 2-way-free)
  float4 stg[6];
  #pragma unroll
  for (int i = 0; i < 6; ++i) {
    const int idx = tid + i * 512;
    const int r = idx >> 4, q = idx & 15;
    const int row = row0 + r;
    float4 v = make_float4(0.f, 0.f, 0.f, 0.f);
    if (idx < STAGE * 16 && row >= 0 && row < S_LEN)
      v = *(const float4*)(xb + ((size_t)row * NCH + (q << 2)));
    stg[i] = v;
  }
  #pragma unroll
  for (int i = 0; i < 6; ++i) {
    const int idx = tid + i * 512;
    if (idx < STAGE * 16)
      *(float4*)(&lds[(idx >> 4) * NCH + ((idx & 15) << 2)]) = stg[i];
  }
  __syncthreads();

  // ---- streaming tap loop over the 77-row window, 20-reg circular buffer
  const int base = ty * RPT;                 // this thread: rows base..base+76
  const float* col = &lds[base * NCH + c];   // column c, stride NCH

  float win[20];
  #pragma unroll
  for (int k = 0; k < 19; ++k) win[k] = col[k * NCH];

  float a6[RPT], a3[RPT], a1[RPT];
  #pragma unroll
  for (int r = 0; r < RPT; ++r) { a6[r] = 0.f; a3[r] = 0.f; a1[r] = 0.f; }

  #pragma unroll
  for (int t = 0; t < 62; ++t) {
    if (t < 58) win[(t + 19) % 20] = col[(t + 19) * NCH];  // prefetch, used @t+4
    const float c6 = W.w6[t];                               // s_load (kernarg)
    #pragma unroll
    for (int r = 0; r < RPT; ++r) a6[r] += c6 * win[(t + r) % 20];
    if (t >= 15 && t <= 46) {
      const float c3 = W.w3[t - 15];
      #pragma unroll
      for (int r = 0; r < RPT; ++r) a3[r] += c3 * win[(t + r) % 20];
    }
    if (t >= 25 && t <= 36) {
      const float c1 = W.w1[t - 25];
      #pragma unroll
      for (int r = 0; r < RPT; ++r) a1[r] += c1 * win[(t + r) % 20];
    }
  }

  // ---- stores: out[(b*3+si)*S + s]*64 + c; 64 lanes x 4 B contiguous per row
  const int srow = s0 + base;
  float* o = out + (((size_t)b * 3) * S_LEN + srow) * NCH + c;  // plane 0 = scale1
  #pragma unroll
  for (int r = 0; r < RPT; ++r) o[(size_t)r * NCH] = a1[r];
  o += (size_t)S_LEN * NCH;                                      // plane 1 = scale3
  #pragma unroll
  for (int r = 0; r < RPT; ++r) o[(size_t)r * NCH] = a3[r];
  o += (size_t)S_LEN * NCH;                                      // plane 2 = scale6
  #pragma unroll
  for (int r = 0; r < RPT; ++r) o[(size_t)r * NCH] = a6[r];
}

// ---------------------------------------------------------------------------
// Host-side weight construction. Replicates pywt/gaus1 exactly:
//   x = linspace(-5,5,1024); step = x[1]-x[0];
//   psi = -2x e^{-x^2}/(pi/2)^{1/4}; int_psi = cumsum(psi)*step  (serial fp64)
//   j = (arange(10a+1)/(a*step)).astype(int64); f = f32(int_psi[j])
// Fused (conv + diff + trim): w_a[t] = -sqrt(a)*(f[t-1]-f[t]), t=0..L,
// f[-1]=f[L]=0.  Index floor decisions are identical fp64 ops -> bit-exact
// (validated rounds 1-2, absmax 1.6e-2 vs 1.0e-1 threshold).
// Runs at graph-capture time only; kernarg is frozen into the graph.
// ---------------------------------------------------------------------------
extern "C" void kernel_launch(void* const* d_in, const int* in_sizes, int n_in,
                              void* d_out, int out_size, void* d_ws, size_t ws_size,
                              hipStream_t stream) {
  (void)n_in; (void)out_size; (void)d_ws; (void)ws_size;
  const float* x = (const float*)d_in[0];
  float* out = (float*)d_out;
  const int B = in_sizes[0] / (S_LEN * NCH);   // 32

  WtArgs W;
  {
    static double ip[1024];
    const double delta = 10.0 / 1023.0;
    const double step  = (-5.0 + delta) + 5.0;       // == numpy x[1]-x[0]
    const double cn    = pow(3.141592653589793 * 0.5, 0.25);
    double s = 0.0;
    for (int i = 0; i < 1024; ++i) {
      const double xi  = (i == 1023) ? 5.0 : ((double)i * delta - 5.0);
      const double psi = (-2.0 * xi) * exp(-(xi * xi)) / cn;
      s += psi;
      ip[i] = s * step;
    }
    const int   as_[3] = {6, 3, 1};
    const int   lf_[3] = {61, 31, 11};               // taps t = 0..lf
    float*      wp_[3] = {W.w6, W.w3, W.w1};
    for (int si = 0; si < 3; ++si) {
      const double denom = (double)as_[si] * step;
      const float  sqa   = (float)sqrt((double)as_[si]);
      const int    lf    = lf_[si];
      for (int t = 0; t <= lf; ++t) {
        float km1 = 0.f, kt = 0.f;
        if (t >= 1)      km1 = (float)ip[(long)(((double)(t - 1)) / denom)];
        if (t <= lf - 1) kt  = (float)ip[(long)(((double)t) / denom)];
        wp_[si][t] = -sqa * (km1 - kt);
      }
    }
  }

  dim3 grid(S_LEN / TILE_S, B);                // (32, 32) = 1024 blocks
  dim3 block(NCH, TY);                         // 512 threads = 8 waves
  hipLaunchKernelGGL(cwt_main, grid, block, 0, stream, x, out, W);
}

// Round 4
// 134.728 us; speedup vs baseline: 1.5055x; 1.5055x over previous
//
#include <hip/hip_runtime.h>
#include <math.h>

#define S_LEN  4096
#define NCH    64
#define TILE_S 128
#define RPT    16          // s-rows per thread
#define TY     8           // 512 threads = 8 waves
#define HALO_L 31
#define STAGE  (TILE_S + 61)   // 189 staged rows
#define WLEN   77              // window rows per thread (61 + RPT)
#define PRE    20              // preloaded window depth (prefetch distance 5 taps)

// 106 fused filter taps, computed on HOST (fp64, bit-matching numpy's index
// math — validated rounds 1-3, absmax 1.56e-2 vs 1.03e-1 threshold) and
// passed BY VALUE -> kernarg segment -> scalar s_load in kernel.
struct WtArgs { float w6[62]; float w3[32]; float w1[12]; };

// ---------------------------------------------------------------------------
// Round-3 post-mortem: `#pragma unroll` on the 62-tap loop did NOT fully
// unroll -> win[(t+r)%20] stayed dynamically indexed -> LLVM kept win[] and
// the accumulators as scratch allocas (VGPR=64, WRITE 3x ideal = scratch
// thrash). This version forces compile-time indices EVERYWHERE via template
// recursion: SROA must promote; no dynamic index can survive to regalloc.
//
// Structure: outer tap T (weight s_load reused 16x, 1 SGPR live), inner r.
// Sliding window: win[T..T+15] live (<=21 VGPRs), win[T+20] loaded at step T
// (first used at step T+5 -> ~135 VALU instrs of slack vs ~120cyc LDS lat).
// Exactly 77 ds_read_b32 per thread.
// ---------------------------------------------------------------------------

template <int T, int R>
struct FmaR {
  static __device__ __forceinline__ void run(const WtArgs& W, const float (&win)[WLEN],
                                             float (&a6)[RPT], float (&a3)[RPT],
                                             float (&a1)[RPT]) {
    a6[R] = fmaf(W.w6[T], win[T + R], a6[R]);
    if constexpr (T >= 15 && T <= 46) a3[R] = fmaf(W.w3[T - 15], win[T + R], a3[R]);
    if constexpr (T >= 25 && T <= 36) a1[R] = fmaf(W.w1[T - 25], win[T + R], a1[R]);
    FmaR<T, R + 1>::run(W, win, a6, a3, a1);
  }
};
template <int T>
struct FmaR<T, RPT> {
  static __device__ __forceinline__ void run(const WtArgs&, const float (&)[WLEN],
                                             float (&)[RPT], float (&)[RPT], float (&)[RPT]) {}
};

template <int T>
struct Step {
  static __device__ __forceinline__ void run(const float* __restrict__ col, const WtArgs& W,
                                             float (&win)[WLEN], float (&a6)[RPT],
                                             float (&a3)[RPT], float (&a1)[RPT]) {
    if constexpr (T + PRE < WLEN) win[T + PRE] = col[(T + PRE) * NCH];
    FmaR<T, 0>::run(W, win, a6, a3, a1);
    Step<T + 1>::run(col, W, win, a6, a3, a1);
  }
};
template <>
struct Step<62> {
  static __device__ __forceinline__ void run(const float* __restrict__, const WtArgs&,
                                             float (&)[WLEN], float (&)[RPT],
                                             float (&)[RPT], float (&)[RPT]) {}
};

template <int K>
struct Pre {
  static __device__ __forceinline__ void run(const float* __restrict__ col, float (&win)[WLEN]) {
    win[K] = col[K * NCH];
    Pre<K + 1>::run(col, win);
  }
};
template <>
struct Pre<PRE> {
  static __device__ __forceinline__ void run(const float* __restrict__, float (&)[WLEN]) {}
};

template <int R>
struct Store {
  static __device__ __forceinline__ void run(float* __restrict__ o1, float* __restrict__ o3,
                                             float* __restrict__ o6, const float (&a6)[RPT],
                                             const float (&a3)[RPT], const float (&a1)[RPT]) {
    o1[(size_t)R * NCH] = a1[R];
    o3[(size_t)R * NCH] = a3[R];
    o6[(size_t)R * NCH] = a6[R];
    Store<R + 1>::run(o1, o3, o6, a6, a3, a1);
  }
};
template <>
struct Store<RPT> {
  static __device__ __forceinline__ void run(float* __restrict__, float* __restrict__,
                                             float* __restrict__, const float (&)[RPT],
                                             const float (&)[RPT], const float (&)[RPT]) {}
};

template <int R>
struct Zero {
  static __device__ __forceinline__ void run(float (&a6)[RPT], float (&a3)[RPT], float (&a1)[RPT]) {
    a6[R] = 0.f; a3[R] = 0.f; a1[R] = 0.f;
    Zero<R + 1>::run(a6, a3, a1);
  }
};
template <>
struct Zero<RPT> {
  static __device__ __forceinline__ void run(float (&)[RPT], float (&)[RPT], float (&)[RPT]) {}
};

__global__ __launch_bounds__(512, 4)
void cwt_main(const float* __restrict__ x, float* __restrict__ out, const WtArgs W) {
  __shared__ __align__(16) float lds[STAGE * NCH];  // 48384 B

  const int c   = threadIdx.x;        // 0..63 (lane = channel)
  const int ty  = threadIdx.y;        // 0..7 (wave)
  const int tid = ty * 64 + c;
  const int b   = blockIdx.y;
  const int s0  = blockIdx.x * TILE_S;
  const float* xb = x + (size_t)b * S_LEN * NCH;
  const int row0 = s0 - HALO_L;

  // ---- stage rows [s0-31 .. s0+157] to LDS as float4 (coalesced, 2-way-free)
  float4 stg[6];
  #pragma unroll
  for (int i = 0; i < 6; ++i) {
    const int idx = tid + i * 512;
    const int r = idx >> 4, q = idx & 15;
    const int row = row0 + r;
    float4 v = make_float4(0.f, 0.f, 0.f, 0.f);
    if (idx < STAGE * 16 && row >= 0 && row < S_LEN)
      v = *(const float4*)(xb + ((size_t)row * NCH + (q << 2)));
    stg[i] = v;
  }
  #pragma unroll
  for (int i = 0; i < 6; ++i) {
    const int idx = tid + i * 512;
    if (idx < STAGE * 16)
      *(float4*)(&lds[(idx >> 4) * NCH + ((idx & 15) << 2)]) = stg[i];
  }
  __syncthreads();

  // ---- streaming tap recursion, all indices compile-time ----
  const int base = ty * RPT;                 // this thread: rows base..base+76
  const float* col = &lds[base * NCH + c];   // column c, stride NCH

  float win[WLEN];
  float a6[RPT], a3[RPT], a1[RPT];
  Zero<0>::run(a6, a3, a1);
  Pre<0>::run(col, win);                     // win[0..19]
  Step<0>::run(col, W, win, a6, a3, a1);     // taps 0..61

  // ---- stores: 64 lanes x 4 B contiguous per row; planes: 0=s1, 1=s3, 2=s6
  const int srow = s0 + base;
  float* o1 = out + (((size_t)b * 3 + 0) * S_LEN + srow) * NCH + c;
  float* o3 = out + (((size_t)b * 3 + 1) * S_LEN + srow) * NCH + c;
  float* o6 = out + (((size_t)b * 3 + 2) * S_LEN + srow) * NCH + c;
  Store<0>::run(o1, o3, o6, a6, a3, a1);
}

// ---------------------------------------------------------------------------
// Host-side weight construction (runs at capture time; kernarg frozen into
// the graph). Replicates pywt/gaus1 exactly:
//   x = linspace(-5,5,1024); step = x[1]-x[0];
//   psi = -2x e^{-x^2}/(pi/2)^{1/4}; int_psi = cumsum(psi)*step (serial fp64)
//   j = (arange(10a+1)/(a*step)).astype(int64); f = f32(int_psi[j])
// Fused (conv + diff + trim): w_a[t] = -sqrt(a)*(f[t-1]-f[t]), f[-1]=f[L]=0.
// ---------------------------------------------------------------------------
extern "C" void kernel_launch(void* const* d_in, const int* in_sizes, int n_in,
                              void* d_out, int out_size, void* d_ws, size_t ws_size,
                              hipStream_t stream) {
  (void)n_in; (void)out_size; (void)d_ws; (void)ws_size;
  const float* x = (const float*)d_in[0];
  float* out = (float*)d_out;
  const int B = in_sizes[0] / (S_LEN * NCH);   // 32

  WtArgs W;
  {
    static double ip[1024];
    const double delta = 10.0 / 1023.0;
    const double step  = (-5.0 + delta) + 5.0;       // == numpy x[1]-x[0]
    const double cn    = pow(3.141592653589793 * 0.5, 0.25);
    double s = 0.0;
    for (int i = 0; i < 1024; ++i) {
      const double xi  = (i == 1023) ? 5.0 : ((double)i * delta - 5.0);
      const double psi = (-2.0 * xi) * exp(-(xi * xi)) / cn;
      s += psi;
      ip[i] = s * step;
    }
    const int   as_[3] = {6, 3, 1};
    const int   lf_[3] = {61, 31, 11};               // taps t = 0..lf
    float*      wp_[3] = {W.w6, W.w3, W.w1};
    for (int si = 0; si < 3; ++si) {
      const double denom = (double)as_[si] * step;
      const float  sqa   = (float)sqrt((double)as_[si]);
      const int    lf    = lf_[si];
      for (int t = 0; t <= lf; ++t) {
        float km1 = 0.f, kt = 0.f;
        if (t >= 1)      km1 = (float)ip[(long)(((double)(t - 1)) / denom)];
        if (t <= lf - 1) kt  = (float)ip[(long)(((double)t) / denom)];
        wp_[si][t] = -sqa * (km1 - kt);
      }
    }
  }

  dim3 grid(S_LEN / TILE_S, B);                // (32, 32) = 1024 blocks
  dim3 block(NCH, TY);                         // 512 threads = 8 waves
  hipLaunchKernelGGL(cwt_main, grid, block, 0, stream, x, out, W);
}